// Round 7
// baseline (419.730 us; speedup 1.0000x reference)
//
#include <hip/hip_runtime.h>

// ContinuousAxialDW: out = x + axialH(x) + axialW(x)
// x: [B=8, C=96, H=256, W=256] fp32
//
// R1: per-channel integer stencils prebuilt into d_ws (tiny pre-pass kernel).
// R2: 4x4 register blocking + XCD swizzle. 129 us, latency-bound.
// R3: cooperative LDS staging (global_load_lds) -> ~106 us. Best so far.
// R4: FAILED (170 us): explicit double-buffer pipeline (bank conflicts, occ drop).
// R5: NEUTRAL: taller tile (24-wave target) -> ~109 us.
// R6: NEUTRAL: 32-wave/CU config (LDS 139KB/CU, VGPR<=64 forced) -> ~109 us.
//     => occupancy is NOT the constraint. Shared invariant of the plateau:
//     barrier-coupled stage->vmcnt(0)drain->compute + LDS round-trip.
// R7 (this round, resubmit after nontemporal-builtin type fix): NO LDS, NO
//     barrier. Direct global b128 reads through L1/L2 (x is L3-resident:
//     measured FETCH 98MB < 201MB input; span overlap and vertical row
//     sharing are L1 hits). 2 rows x 4 cols per thread, ~15 independent b128
//     loads per thread, freely in flight. Nontemporal stores keep the write
//     stream from evicting x out of L2/L3.

constexpr int B = 8, C = 96, H = 256, W = 256;
constexpr int KT = 7;              // taps per axis
constexpr int HALO = 8;            // integer-tap radius (covers r <= ~2.3)
constexpr int NW = 2 * HALO + 1;   // 17
constexpr int RPT = 2;             // output rows per thread
constexpr int RPB = 8;             // output rows per WG (4 waves x 2)
constexpr int TILES = B * C * (H / RPB);   // 24576
constexpr int TPX = TILES / 8;             // 3072 per XCD

typedef float f32x4 __attribute__((ext_vector_type(4)));   // native vec for nt-store

// d_ws layout: [0 .. C*NW)      = wtv (vertical / H-axis stencil)
//              [C*NW .. 2*C*NW) = wth (horizontal / W-axis stencil)

__global__ __launch_bounds__(64) void build_stencils(
    const float* __restrict__ wh,
    const float* __restrict__ ww,
    const float* __restrict__ rp,
    float* __restrict__ ws)
{
    const int c = blockIdx.x;        // 0..C-1
    const int d = threadIdx.x;       // 0..63, only d < NW active
    if (d >= NW) return;

    float r = rp[0];
    if (r < 1.0f) r = 1.0f;

    float av = 0.f, aw = 0.f;
#pragma unroll
    for (int i = 0; i < KT; ++i) {
        float s   = (float)(i - 3) * r;   // pixel shift of tap i
        float d0f = floorf(s);
        int   d0  = (int)d0f;
        float f   = s - d0f;              // constant bilinear frac
        float thv = wh[c * KT + i];
        float twv = ww[c * KT + i];
        if (d - HALO == d0)     { av = fmaf(thv, 1.f - f, av); aw = fmaf(twv, 1.f - f, aw); }
        if (d - HALO == d0 + 1) { av = fmaf(thv, f, av);       aw = fmaf(twv, f, aw); }
    }
    ws[c * NW + d]          = av;
    ws[C * NW + c * NW + d] = aw;
}

__global__ __launch_bounds__(256, 8) void axialdw_kernel(
    const float* __restrict__ x,
    const float* __restrict__ ws,
    float* __restrict__ out)
{
    // ---- XCD-aware bijective swizzle (nwg = 24576, divisible by 8) ----
    const int bid = blockIdx.x;
    const int lb  = (bid & 7) * TPX + (bid >> 3);

    const int hb   = lb & (H / RPB - 1);         // h-chunk within plane (0..31)
    const int bc   = lb >> 5;                    // (b,c) plane index
    const int c    = bc % C;
    const int wave = threadIdx.x >> 6;           // 0..3
    const int lane = threadIdx.x & 63;
    const int w0   = lane * 4;
    const int h0   = hb * RPB + wave * RPT;      // thread's first output row

    // block-uniform stencils (uniform c -> scalar loads, SGPR-resident)
    float wtv[NW], wth[NW];
#pragma unroll
    for (int d = 0; d < NW; ++d) {
        wtv[d] = ws[c * NW + d];
        wth[d] = ws[C * NW + c * NW + d];
    }

    const float* plane = x + (size_t)bc * (H * W);

    float acc[RPT][4];
#pragma unroll
    for (int rr = 0; rr < RPT; ++rr)
#pragma unroll
        for (int e = 0; e < 4; ++e) acc[rr][e] = 0.f;

    // ---- vertical: source row h0+t-HALO feeds rr via tap d = t - rr ----
    // All loads are independent global b128 (L1/L2-hot: shared across waves
    // and neighboring WGs); uniform skips for zero taps and OOB rows.
#pragma unroll
    for (int t = 0; t < NW + RPT - 1; ++t) {     // 18
        const float g0 = (t < NW) ? wtv[t] : 0.f;            // tap into rr=0
        const float g1 = (t >= 1) ? wtv[t - 1] : 0.f;        // tap into rr=1
        if (g0 == 0.f && g1 == 0.f) continue;                // uniform skip
        const int hh = h0 + t - HALO;
        if (hh < 0 || hh >= H) continue;                     // uniform skip
        const float4 v = *(const float4*)(plane + (size_t)hh * W + w0);
        if (g0 != 0.f) {
            acc[0][0] = fmaf(g0, v.x, acc[0][0]);
            acc[0][1] = fmaf(g0, v.y, acc[0][1]);
            acc[0][2] = fmaf(g0, v.z, acc[0][2]);
            acc[0][3] = fmaf(g0, v.w, acc[0][3]);
        }
        if (g1 != 0.f) {
            acc[1][0] = fmaf(g1, v.x, acc[1][0]);
            acc[1][1] = fmaf(g1, v.y, acc[1][1]);
            acc[1][2] = fmaf(g1, v.z, acc[1][2]);
            acc[1][3] = fmaf(g1, v.w, acc[1][3]);
        }
    }

    // ---- horizontal + residual per row, nontemporal store ----
    float* obase = out + (size_t)bc * (H * W) + (size_t)h0 * W + w0;
#pragma unroll
    for (int rr = 0; rr < RPT; ++rr) {
        const float* row = plane + (size_t)(h0 + rr) * W;

        // span [w0-8, w0+12): 5 b128. Edge float4s are provably fully-OOB
        // (offsets & W multiples of 4) -> branchless clamp-address + mask.
        float sp[20];
#pragma unroll
        for (int k = 0; k < 5; ++k) {
            const int wb = w0 - 8 + 4 * k;
            float4 v;
            if (k == 2) {                        // always in range
                v = *(const float4*)(row + wb);
            } else {
                const bool ok = ((unsigned)wb <= (unsigned)(W - 4));
                v = *(const float4*)(row + (ok ? wb : 0));
                const float m = ok ? 1.f : 0.f;
                v.x *= m; v.y *= m; v.z *= m; v.w *= m;
            }
            sp[4 * k + 0] = v.x; sp[4 * k + 1] = v.y;
            sp[4 * k + 2] = v.z; sp[4 * k + 3] = v.w;
        }

#pragma unroll
        for (int e = 0; e < 4; ++e)
            acc[rr][e] += sp[HALO + e];          // residual x
#pragma unroll
        for (int d = 0; d < NW; ++d) {
            const float wg = wth[d];
            if (wg != 0.f) {                     // uniform zero-tap skip
#pragma unroll
                for (int e = 0; e < 4; ++e)
                    acc[rr][e] = fmaf(wg, sp[d + e], acc[rr][e]);
            }
        }

        f32x4 o;
        o.x = acc[rr][0]; o.y = acc[rr][1]; o.z = acc[rr][2]; o.w = acc[rr][3];
        __builtin_nontemporal_store(o, (f32x4*)(obase + (size_t)rr * W));
    }
}

extern "C" void kernel_launch(void* const* d_in, const int* in_sizes, int n_in,
                              void* d_out, int out_size, void* d_ws, size_t ws_size,
                              hipStream_t stream) {
    const float* x  = (const float*)d_in[0];
    const float* wh = (const float*)d_in[1];
    const float* ww = (const float*)d_in[2];
    const float* rp = (const float*)d_in[3];
    float* out = (float*)d_out;
    float* ws  = (float*)d_ws;

    build_stencils<<<C, 64, 0, stream>>>(wh, ww, rp, ws);
    axialdw_kernel<<<TILES, 256, 0, stream>>>(x, ws, out);
}